// Round 2
// baseline (1118.831 us; speedup 1.0000x reference)
//
#include <hip/hip_runtime.h>
#include <math.h>

#define N_CELLS 8192
#define DIM 512
#define TILE 128
#define BK 16
#define LDP (TILE + 4)

// ---------- helpers: order-preserving float<->uint key ----------
__device__ __forceinline__ unsigned fkey(float f) {
    unsigned u = __float_as_uint(f);
    return (u & 0x80000000u) ? ~u : (u | 0x80000000u);
}
__device__ __forceinline__ float finv(unsigned k) {
    unsigned u = (k & 0x80000000u) ? (k ^ 0x80000000u) : ~k;
    return __uint_as_float(u);
}

// ---------- kernel A: squared norms + zero the output scalar ----------
__global__ __launch_bounds__(256) void norms_kernel(const float* __restrict__ E,
                                                    float* __restrict__ norms,
                                                    float* __restrict__ out) {
    if (blockIdx.x == 0 && threadIdx.x == 0) out[0] = 0.0f;
    const int wave = threadIdx.x >> 6, lane = threadIdx.x & 63;
    const int row = blockIdx.x * 4 + wave;
    const float4* e4 = (const float4*)(E + (size_t)row * DIM);
    float4 a = e4[lane], b = e4[lane + 64];
    float s = a.x*a.x + a.y*a.y + a.z*a.z + a.w*a.w
            + b.x*b.x + b.y*b.y + b.z*b.z + b.w*b.w;
    #pragma unroll
    for (int off = 32; off > 0; off >>= 1) s += __shfl_down(s, off, 64);
    if (lane == 0) norms[row] = s;
}

// ---------- kernel B: fp32 tiled GEMM -> distance-matrix row chunk ----------
// D[gi][gj] = n_gi + n_gj - 2*dot(E_gi,E_gj); +1e10 on the diagonal.
// Writes rows [r0, r0+gridDim.y*TILE) into Dm (chunk-local row index).
__global__ __launch_bounds__(256) void dist_chunk_kernel(const float* __restrict__ E,
                                                         const float* __restrict__ norms,
                                                         float* __restrict__ Dm,
                                                         int r0) {
    __shared__ float As[BK][LDP];
    __shared__ float Bs[BK][LDP];
    const int bx = blockIdx.x, by = blockIdx.y;
    const int t = threadIdx.x;
    const int tx = t & 15, ty = t >> 4;
    const int lr = t >> 2;          // 0..63
    const int lk = (t & 3) * 4;     // 0,4,8,12

    float acc[8][8] = {};

    const float* Ab = E + (size_t)(r0 + by * TILE + lr) * DIM + lk;
    const float* Bb = E + (size_t)(bx * TILE + lr) * DIM + lk;

    for (int k0 = 0; k0 < DIM; k0 += BK) {
        float4 a0 = *(const float4*)(Ab + k0);
        float4 a1 = *(const float4*)(Ab + (size_t)64 * DIM + k0);
        float4 b0 = *(const float4*)(Bb + k0);
        float4 b1 = *(const float4*)(Bb + (size_t)64 * DIM + k0);
        __syncthreads();
        As[lk+0][lr]    = a0.x; As[lk+1][lr]    = a0.y; As[lk+2][lr]    = a0.z; As[lk+3][lr]    = a0.w;
        As[lk+0][lr+64] = a1.x; As[lk+1][lr+64] = a1.y; As[lk+2][lr+64] = a1.z; As[lk+3][lr+64] = a1.w;
        Bs[lk+0][lr]    = b0.x; Bs[lk+1][lr]    = b0.y; Bs[lk+2][lr]    = b0.z; Bs[lk+3][lr]    = b0.w;
        Bs[lk+0][lr+64] = b1.x; Bs[lk+1][lr+64] = b1.y; Bs[lk+2][lr+64] = b1.z; Bs[lk+3][lr+64] = b1.w;
        __syncthreads();
        #pragma unroll
        for (int kk = 0; kk < BK; kk++) {
            float av[8], bv[8];
            *(float4*)&av[0] = *(const float4*)&As[kk][ty*8];
            *(float4*)&av[4] = *(const float4*)&As[kk][ty*8+4];
            *(float4*)&bv[0] = *(const float4*)&Bs[kk][tx*8];
            *(float4*)&bv[4] = *(const float4*)&Bs[kk][tx*8+4];
            #pragma unroll
            for (int r = 0; r < 8; r++)
                #pragma unroll
                for (int c = 0; c < 8; c++)
                    acc[r][c] = fmaf(av[r], bv[c], acc[r][c]);
        }
    }

    const int gi0 = r0 + by*TILE + ty*8;   // global row
    const int li0 = by*TILE + ty*8;        // chunk-local row
    const int gj0 = bx*TILE + tx*8;
    float nj[8];
    #pragma unroll
    for (int c = 0; c < 8; c++) nj[c] = norms[gj0 + c];
    #pragma unroll
    for (int r = 0; r < 8; r++) {
        const int gi = gi0 + r;
        const float ni = norms[gi];
        float o[8];
        #pragma unroll
        for (int c = 0; c < 8; c++) {
            float d = ni + nj[c] - 2.0f * acc[r][c];
            if (gi == gj0 + c) d += 1e10f;
            o[c] = d;
        }
        float* dst = Dm + (size_t)(li0 + r) * N_CELLS + gj0;
        *(float4*)(dst)     = *(float4*)&o[0];
        *(float4*)(dst + 4) = *(float4*)&o[4];
    }
}

// ---------- shared tail: kth-order-statistic + masked-softmax entropy ----------
// rowb: full row of distances in LDS. lst: per-thread sorted top-15 (registers).
__device__ __forceinline__ void finish_row(const float* rowb,
                                           float lst[15],
                                           const int* __restrict__ labels,
                                           float* __restrict__ out) {
    __shared__ float w0s[4], w14s[4];
    __shared__ int cnt;
    __shared__ float zz[4], r0s[4], r1s[4], r2s[4];

    const int t = threadIdx.x;
    const int lane = t & 63, wave = t >> 6;

    // Row min (lst[0]) and upper bound for the 15th (min over threads of lst[14]).
    float m0 = lst[0], m14 = lst[14];
    #pragma unroll
    for (int off = 32; off > 0; off >>= 1) {
        m0  = fminf(m0,  __shfl_down(m0,  off, 64));
        m14 = fminf(m14, __shfl_down(m14, off, 64));
    }
    if (lane == 0) { w0s[wave] = m0; w14s[wave] = m14; }
    __syncthreads();
    const float dmin = fminf(fminf(w0s[0], w0s[1]), fminf(w0s[2], w0s[3]));
    const float ub   = fminf(fminf(w14s[0], w14s[1]), fminf(w14s[2], w14s[3]));

    // Exact 15th order statistic via bit-space binary search counting over the
    // 256*15 register candidates (global top-15 is a subset of these).
    unsigned keys[15];
    #pragma unroll
    for (int k = 0; k < 15; k++) keys[k] = fkey(lst[k]);

    unsigned lo = fkey(dmin), hi = fkey(ub);
    int iter = 0;
    while (lo < hi && iter < 34) {
        iter++;
        const unsigned mid = lo + ((hi - lo) >> 1);
        int c = 0;
        #pragma unroll
        for (int k = 0; k < 15; k++) c += (keys[k] <= mid) ? 1 : 0;
        #pragma unroll
        for (int off = 32; off > 0; off >>= 1) c += __shfl_down(c, off, 64);
        __syncthreads();
        if (t == 0) cnt = 0;
        __syncthreads();
        if (lane == 0) atomicAdd(&cnt, c);
        __syncthreads();
        const int total = cnt;
        if (total >= 15) hi = mid; else lo = mid + 1;
    }
    const float kth = finv(hi);

    // Pass 2: Z = sum exp(dmin-d), per-label masked sums.
    float z = 0.f, s0 = 0.f, s1 = 0.f, s2 = 0.f;
    for (int s = 0; s < N_CELLS / 256; s++) {
        const int j = s * 256 + t;
        const float d = rowb[j];
        const float w = __expf(dmin - d);
        const float msk = 1.0f / (1.0f + __expf(d - kth));   // sigmoid(kth - d)
        const float p = w * msk;
        const int lab = labels[j];
        z  += w;
        s0 += (lab == 0) ? p : 0.f;
        s1 += (lab == 1) ? p : 0.f;
        s2 += (lab == 2) ? p : 0.f;
    }
    #pragma unroll
    for (int off = 32; off > 0; off >>= 1) {
        z  += __shfl_down(z,  off, 64);
        s0 += __shfl_down(s0, off, 64);
        s1 += __shfl_down(s1, off, 64);
        s2 += __shfl_down(s2, off, 64);
    }
    if (lane == 0) { zz[wave] = z; r0s[wave] = s0; r1s[wave] = s1; r2s[wave] = s2; }
    __syncthreads();
    if (t == 0) {
        const float Z  = zz[0]+zz[1]+zz[2]+zz[3];
        const float S0 = r0s[0]+r0s[1]+r0s[2]+r0s[3];
        const float S1 = r1s[0]+r1s[1]+r1s[2]+r1s[3];
        const float S2 = r2s[0]+r2s[1]+r2s[2]+r2s[3];
        const float ssum = S0 + S1 + S2;
        // normalized weights: (w/Z*m)/(sum(w/Z*m)+EPS) = w*m/(ssum + EPS*Z)
        const float denom = ssum + 1e-8f * Z;
        const float q0 = S0/denom, q1 = S1/denom, q2 = S2/denom;
        const float H = -(q0*logf(q0+1e-8f) + q1*logf(q1+1e-8f) + q2*logf(q2+1e-8f));
        const float contrib = -(H / (logf(3.0f) + 1e-8f)) * (1.0f / N_CELLS);
        atomicAdd(out, contrib);
    }
}

// ---------- kernel C: per-row loss over a materialized D chunk ----------
__global__ __launch_bounds__(256) void loss_kernel(const float* __restrict__ Dm,
                                                   const int* __restrict__ labels,
                                                   float* __restrict__ out) {
    __shared__ float rowb[N_CELLS];          // 32 KB row cache
    const int t = threadIdx.x;
    const float* drow = Dm + (size_t)blockIdx.x * N_CELLS;

    float lst[15];
    #pragma unroll
    for (int k = 0; k < 15; k++) lst[k] = 3.0e38f;

    for (int s = 0; s < N_CELLS / 256; s++) {
        const int j = s * 256 + t;
        float d = drow[j];
        rowb[j] = d;
        float v = d;
        #pragma unroll
        for (int k = 0; k < 15; k++) {
            float lo2 = fminf(lst[k], v);
            v = fmaxf(lst[k], v);
            lst[k] = lo2;
        }
    }
    finish_row(rowb, lst, labels, out);
}

// ---------- fallback: fully fused, recomputes dots from E (tiny workspace) ----------
__global__ __launch_bounds__(256) void fused_kernel(const float* __restrict__ E,
                                                    const float* __restrict__ norms,
                                                    const int* __restrict__ labels,
                                                    float* __restrict__ out) {
    __shared__ float rowb[N_CELLS];          // 32 KB
    __shared__ float ei[DIM];                // 2 KB
    const int i = blockIdx.x;
    const int t = threadIdx.x;

    for (int k = t; k < DIM; k += 256) ei[k] = E[(size_t)i * DIM + k];
    __syncthreads();
    const float ni = norms[i];

    float lst[15];
    #pragma unroll
    for (int k = 0; k < 15; k++) lst[k] = 3.0e38f;

    for (int s = 0; s < N_CELLS / 256; s++) {
        const int j = s * 256 + t;
        const float* ej = E + (size_t)j * DIM;
        float dot = 0.f;
        #pragma unroll 4
        for (int k = 0; k < DIM; k += 4) {
            float4 e4 = *(const float4*)(ej + k);
            dot += ei[k]*e4.x + ei[k+1]*e4.y + ei[k+2]*e4.z + ei[k+3]*e4.w;
        }
        float d = ni + norms[j] - 2.0f * dot;
        if (j == i) d += 1e10f;
        rowb[j] = d;
        float v = d;
        #pragma unroll
        for (int k = 0; k < 15; k++) {
            float lo2 = fminf(lst[k], v);
            v = fmaxf(lst[k], v);
            lst[k] = lo2;
        }
    }
    finish_row(rowb, lst, labels, out);
}

// ---------- launcher ----------
// ws layout: [0, 32KB) sq_norms; [32KB, 32KB + R*32KB) D row-chunk.
// R adapts to ws_size (multiple of 128, capped at 2048 rows = 64 MB so the
// chunk stays LLC-resident). If even 128 rows don't fit, use the fused
// recompute fallback (needs only the 32 KB norms buffer).
extern "C" void kernel_launch(void* const* d_in, const int* in_sizes, int n_in,
                              void* d_out, int out_size, void* d_ws, size_t ws_size,
                              hipStream_t stream) {
    const float* E = (const float*)d_in[0];
    const int* labels = (const int*)d_in[1];
    float* out = (float*)d_out;
    float* norms = (float*)d_ws;
    float* Dm = (float*)((char*)d_ws + 32768);

    const size_t rowbytes = (size_t)N_CELLS * sizeof(float);   // 32 KB
    const size_t avail = (ws_size > 32768) ? (ws_size - 32768) : 0;
    int R = (int)((avail / rowbytes) / TILE) * TILE;
    if (R > 2048) R = 2048;

    norms_kernel<<<N_CELLS / 4, 256, 0, stream>>>(E, norms, out);

    if (R >= TILE) {
        for (int r0 = 0; r0 < N_CELLS; r0 += R) {
            const int rows = (N_CELLS - r0 < R) ? (N_CELLS - r0) : R;
            dim3 g(N_CELLS / TILE, rows / TILE);
            dist_chunk_kernel<<<g, 256, 0, stream>>>(E, norms, Dm, r0);
            loss_kernel<<<rows, 256, 0, stream>>>(Dm, labels, out);
        }
    } else {
        fused_kernel<<<N_CELLS, 256, 0, stream>>>(E, norms, labels, out);
    }
}

// Round 3
// 529.786 us; speedup vs baseline: 2.1119x; 2.1119x over previous
//
#include <hip/hip_runtime.h>
#include <math.h>

#define N_CELLS 8192
#define DIM 512
#define TILE 128

typedef float f32x4 __attribute__((ext_vector_type(4)));
typedef short s16x8 __attribute__((ext_vector_type(8)));

#define AS1U(p) ((const __attribute__((address_space(1))) unsigned int*)(p))
#define AS3U(p) ((__attribute__((address_space(3))) unsigned int*)(p))

// ---------- helpers: order-preserving float<->uint key ----------
__device__ __forceinline__ unsigned fkey(float f) {
    unsigned u = __float_as_uint(f);
    return (u & 0x80000000u) ? ~u : (u | 0x80000000u);
}
__device__ __forceinline__ float finv(unsigned k) {
    unsigned u = (k & 0x80000000u) ? (k ^ 0x80000000u) : ~k;
    return __uint_as_float(u);
}
// round-to-nearest-even fp32 -> bf16 bits
__device__ __forceinline__ unsigned short f2bf_bits(float x) {
    unsigned u = __float_as_uint(x);
    u += 0x7fffu + ((u >> 16) & 1u);
    return (unsigned short)(u >> 16);
}

// ---------- kernel A: squared norms (exact fp32) + zero output ----------
__global__ __launch_bounds__(256) void norms_kernel(const float* __restrict__ E,
                                                    float* __restrict__ norms,
                                                    float* __restrict__ out) {
    if (blockIdx.x == 0 && threadIdx.x == 0) out[0] = 0.0f;
    const int wave = threadIdx.x >> 6, lane = threadIdx.x & 63;
    const int row = blockIdx.x * 4 + wave;
    const float4* e4 = (const float4*)(E + (size_t)row * DIM);
    float4 a = e4[lane], b = e4[lane + 64];
    float s = a.x*a.x + a.y*a.y + a.z*a.z + a.w*a.w
            + b.x*b.x + b.y*b.y + b.z*b.z + b.w*b.w;
    #pragma unroll
    for (int off = 32; off > 0; off >>= 1) s += __shfl_down(s, off, 64);
    if (lane == 0) norms[row] = s;
}

// ---------- kernel A2: fp32 -> (hi, lo) bf16 split ----------
__global__ __launch_bounds__(256) void convert_kernel(const float* __restrict__ E,
                                                      unsigned short* __restrict__ Eh,
                                                      unsigned short* __restrict__ El) {
    const int idx = (blockIdx.x * 256 + threadIdx.x) * 4;
    float4 v = *(const float4*)(E + idx);
    ushort4 h, l;
    h.x = f2bf_bits(v.x); h.y = f2bf_bits(v.y); h.z = f2bf_bits(v.z); h.w = f2bf_bits(v.w);
    l.x = f2bf_bits(v.x - __uint_as_float((unsigned)h.x << 16));
    l.y = f2bf_bits(v.y - __uint_as_float((unsigned)h.y << 16));
    l.z = f2bf_bits(v.z - __uint_as_float((unsigned)h.z << 16));
    l.w = f2bf_bits(v.w - __uint_as_float((unsigned)h.w << 16));
    *(ushort4*)(Eh + idx) = h;
    *(ushort4*)(El + idx) = l;
}

// ---------- kernel B: MFMA split-bf16 distance GEMM (row chunk) ----------
// dot(e_i,e_j) ~= hi.hi + hi.lo + lo.hi (lo.lo dropped, ~1e-4 abs).
// D[gi][gj] = n_gi + n_gj - 2*dot; +1e10 diagonal. 128x128 tile, BK=32.
__device__ __forceinline__ s16x8 frag_ld(const unsigned short* tile, int rowbase, int lane) {
    const int row = rowbase + (lane & 15);
    const int k8 = (lane >> 4) * 8;
    return *(const s16x8*)(tile + row * 32 + k8);
}

__global__ __launch_bounds__(256) void dist_mfma_kernel(const unsigned short* __restrict__ Eh,
                                                        const unsigned short* __restrict__ El,
                                                        const float* __restrict__ norms,
                                                        float* __restrict__ Dm,
                                                        int r0) {
    __shared__ unsigned short Ah[TILE * 32];
    __shared__ unsigned short Al[TILE * 32];
    __shared__ unsigned short Bh[TILE * 32];
    __shared__ unsigned short Bl[TILE * 32];

    const int t = threadIdx.x;
    const int lane = t & 63;
    const int w = t >> 6;
    const int wr = w >> 1, wc = w & 1;

    const int arow = r0 + blockIdx.y * TILE;   // global rows (i)
    const int brow = blockIdx.x * TILE;        // global cols (j)

    const int srow = t >> 2;        // 0..63: staged row within 64-row group
    const int sk = (t & 3) * 8;     // staged k element offset

    f32x4 acc[4][4];
    #pragma unroll
    for (int a = 0; a < 4; a++)
        #pragma unroll
        for (int b = 0; b < 4; b++)
            acc[a][b] = (f32x4){0.f, 0.f, 0.f, 0.f};

    for (int k0 = 0; k0 < DIM; k0 += 32) {
        __syncthreads();
        {
            const size_t ga0 = (size_t)(arow + srow) * DIM + k0 + sk;
            const size_t gb0 = (size_t)(brow + srow) * DIM + k0 + sk;
            const size_t stp = (size_t)64 * DIM;
            __builtin_amdgcn_global_load_lds(AS1U(Eh + ga0),       AS3U((char*)Ah + t*16),        16, 0, 0);
            __builtin_amdgcn_global_load_lds(AS1U(Eh + ga0 + stp), AS3U((char*)Ah + 4096 + t*16), 16, 0, 0);
            __builtin_amdgcn_global_load_lds(AS1U(El + ga0),       AS3U((char*)Al + t*16),        16, 0, 0);
            __builtin_amdgcn_global_load_lds(AS1U(El + ga0 + stp), AS3U((char*)Al + 4096 + t*16), 16, 0, 0);
            __builtin_amdgcn_global_load_lds(AS1U(Eh + gb0),       AS3U((char*)Bh + t*16),        16, 0, 0);
            __builtin_amdgcn_global_load_lds(AS1U(Eh + gb0 + stp), AS3U((char*)Bh + 4096 + t*16), 16, 0, 0);
            __builtin_amdgcn_global_load_lds(AS1U(El + gb0),       AS3U((char*)Bl + t*16),        16, 0, 0);
            __builtin_amdgcn_global_load_lds(AS1U(El + gb0 + stp), AS3U((char*)Bl + 4096 + t*16), 16, 0, 0);
        }
        __syncthreads();

        s16x8 ah[4], al[4], bh[4], bl[4];
        #pragma unroll
        for (int tm = 0; tm < 4; tm++) {
            ah[tm] = frag_ld(Ah, wr * 64 + tm * 16, lane);
            al[tm] = frag_ld(Al, wr * 64 + tm * 16, lane);
        }
        #pragma unroll
        for (int tn = 0; tn < 4; tn++) {
            bh[tn] = frag_ld(Bh, wc * 64 + tn * 16, lane);
            bl[tn] = frag_ld(Bl, wc * 64 + tn * 16, lane);
        }
        #pragma unroll
        for (int tm = 0; tm < 4; tm++)
            #pragma unroll
            for (int tn = 0; tn < 4; tn++) {
                acc[tm][tn] = __builtin_amdgcn_mfma_f32_16x16x32_bf16(ah[tm], bh[tn], acc[tm][tn], 0, 0, 0);
                acc[tm][tn] = __builtin_amdgcn_mfma_f32_16x16x32_bf16(ah[tm], bl[tn], acc[tm][tn], 0, 0, 0);
                acc[tm][tn] = __builtin_amdgcn_mfma_f32_16x16x32_bf16(al[tm], bh[tn], acc[tm][tn], 0, 0, 0);
            }
    }

    // epilogue: C/D layout col=lane&15, row=(lane>>4)*4+reg  [m89-verified]
    const int colb = brow + wc * 64 + (lane & 15);
    const int rowb = arow + wr * 64 + (lane >> 4) * 4;
    #pragma unroll
    for (int tn = 0; tn < 4; tn++) {
        const int col = colb + tn * 16;
        const float nj = norms[col];
        #pragma unroll
        for (int tm = 0; tm < 4; tm++) {
            #pragma unroll
            for (int r = 0; r < 4; r++) {
                const int row = rowb + tm * 16 + r;
                float d = norms[row] + nj - 2.0f * acc[tm][tn][r];
                if (row == col) d += 1e10f;
                Dm[(size_t)(row - r0) * N_CELLS + col] = d;
            }
        }
    }
}

// ---------- shared tail: kth-order-statistic + masked-softmax entropy ----------
__device__ __forceinline__ void finish_row(const float* rowb,
                                           float lst[15],
                                           const int* __restrict__ labels,
                                           float* __restrict__ out) {
    __shared__ float w0s[4], w14s[4];
    __shared__ int cnt;
    __shared__ float zz[4], r0s[4], r1s[4], r2s[4];

    const int t = threadIdx.x;
    const int lane = t & 63, wave = t >> 6;

    float m0 = lst[0], m14 = lst[14];
    #pragma unroll
    for (int off = 32; off > 0; off >>= 1) {
        m0  = fminf(m0,  __shfl_down(m0,  off, 64));
        m14 = fminf(m14, __shfl_down(m14, off, 64));
    }
    if (lane == 0) { w0s[wave] = m0; w14s[wave] = m14; }
    __syncthreads();
    const float dmin = fminf(fminf(w0s[0], w0s[1]), fminf(w0s[2], w0s[3]));
    const float ub   = fminf(fminf(w14s[0], w14s[1]), fminf(w14s[2], w14s[3]));

    unsigned keys[15];
    #pragma unroll
    for (int k = 0; k < 15; k++) keys[k] = fkey(lst[k]);

    unsigned lo = fkey(dmin), hi = fkey(ub);
    int iter = 0;
    while (lo < hi && iter < 34) {
        iter++;
        const unsigned mid = lo + ((hi - lo) >> 1);
        int c = 0;
        #pragma unroll
        for (int k = 0; k < 15; k++) c += (keys[k] <= mid) ? 1 : 0;
        #pragma unroll
        for (int off = 32; off > 0; off >>= 1) c += __shfl_down(c, off, 64);
        __syncthreads();
        if (t == 0) cnt = 0;
        __syncthreads();
        if (lane == 0) atomicAdd(&cnt, c);
        __syncthreads();
        const int total = cnt;
        if (total >= 15) hi = mid; else lo = mid + 1;
    }
    const float kth = finv(hi);

    float z = 0.f, s0 = 0.f, s1 = 0.f, s2 = 0.f;
    for (int s = 0; s < N_CELLS / 256; s++) {
        const int j = s * 256 + t;
        const float d = rowb[j];
        const float w = __expf(dmin - d);
        const float msk = 1.0f / (1.0f + __expf(d - kth));
        const float p = w * msk;
        const int lab = labels[j];
        z  += w;
        s0 += (lab == 0) ? p : 0.f;
        s1 += (lab == 1) ? p : 0.f;
        s2 += (lab == 2) ? p : 0.f;
    }
    #pragma unroll
    for (int off = 32; off > 0; off >>= 1) {
        z  += __shfl_down(z,  off, 64);
        s0 += __shfl_down(s0, off, 64);
        s1 += __shfl_down(s1, off, 64);
        s2 += __shfl_down(s2, off, 64);
    }
    if (lane == 0) { zz[wave] = z; r0s[wave] = s0; r1s[wave] = s1; r2s[wave] = s2; }
    __syncthreads();
    if (t == 0) {
        const float Z  = zz[0]+zz[1]+zz[2]+zz[3];
        const float S0 = r0s[0]+r0s[1]+r0s[2]+r0s[3];
        const float S1 = r1s[0]+r1s[1]+r1s[2]+r1s[3];
        const float S2 = r2s[0]+r2s[1]+r2s[2]+r2s[3];
        const float ssum = S0 + S1 + S2;
        const float denom = ssum + 1e-8f * Z;
        const float q0 = S0/denom, q1 = S1/denom, q2 = S2/denom;
        const float H = -(q0*logf(q0+1e-8f) + q1*logf(q1+1e-8f) + q2*logf(q2+1e-8f));
        const float contrib = -(H / (logf(3.0f) + 1e-8f)) * (1.0f / N_CELLS);
        atomicAdd(out, contrib);
    }
}

// ---------- kernel C: per-row loss over a materialized D chunk ----------
__global__ __launch_bounds__(256) void loss_kernel(const float* __restrict__ Dm,
                                                   const int* __restrict__ labels,
                                                   float* __restrict__ out) {
    __shared__ float rowb[N_CELLS];
    const int t = threadIdx.x;
    const float* drow = Dm + (size_t)blockIdx.x * N_CELLS;

    float lst[15];
    #pragma unroll
    for (int k = 0; k < 15; k++) lst[k] = 3.0e38f;

    for (int s = 0; s < N_CELLS / 256; s++) {
        const int j = s * 256 + t;
        float d = drow[j];
        rowb[j] = d;
        float v = d;
        #pragma unroll
        for (int k = 0; k < 15; k++) {
            float lo2 = fminf(lst[k], v);
            v = fmaxf(lst[k], v);
            lst[k] = lo2;
        }
    }
    finish_row(rowb, lst, labels, out);
}

// ---------- fallback: fully fused fp32, recomputes dots from E ----------
__global__ __launch_bounds__(256) void fused_kernel(const float* __restrict__ E,
                                                    const float* __restrict__ norms,
                                                    const int* __restrict__ labels,
                                                    float* __restrict__ out) {
    __shared__ float rowb[N_CELLS];
    __shared__ float ei[DIM];
    const int i = blockIdx.x;
    const int t = threadIdx.x;

    for (int k = t; k < DIM; k += 256) ei[k] = E[(size_t)i * DIM + k];
    __syncthreads();
    const float ni = norms[i];

    float lst[15];
    #pragma unroll
    for (int k = 0; k < 15; k++) lst[k] = 3.0e38f;

    for (int s = 0; s < N_CELLS / 256; s++) {
        const int j = s * 256 + t;
        const float* ej = E + (size_t)j * DIM;
        float dot = 0.f;
        #pragma unroll 4
        for (int k = 0; k < DIM; k += 4) {
            float4 e4 = *(const float4*)(ej + k);
            dot += ei[k]*e4.x + ei[k+1]*e4.y + ei[k+2]*e4.z + ei[k+3]*e4.w;
        }
        float d = ni + norms[j] - 2.0f * dot;
        if (j == i) d += 1e10f;
        rowb[j] = d;
        float v = d;
        #pragma unroll
        for (int k = 0; k < 15; k++) {
            float lo2 = fminf(lst[k], v);
            v = fmaxf(lst[k], v);
            lst[k] = lo2;
        }
    }
    finish_row(rowb, lst, labels, out);
}

// ---------- launcher ----------
// ws layout: [0,32KB) norms | [32KB,+8MB) Eh | [+8MB,+8MB) El | rest: D chunk.
// R adapts to ws_size (multiple of 128, cap 2048 rows = 64MB, LLC-resident).
extern "C" void kernel_launch(void* const* d_in, const int* in_sizes, int n_in,
                              void* d_out, int out_size, void* d_ws, size_t ws_size,
                              hipStream_t stream) {
    const float* E = (const float*)d_in[0];
    const int* labels = (const int*)d_in[1];
    float* out = (float*)d_out;

    char* p = (char*)d_ws;
    float* norms = (float*)p;                 p += 32768;
    unsigned short* Eh = (unsigned short*)p;  p += (size_t)N_CELLS * DIM * 2;
    unsigned short* El = (unsigned short*)p;  p += (size_t)N_CELLS * DIM * 2;
    float* Dm = (float*)p;

    const size_t fixed = 32768 + 2 * (size_t)N_CELLS * DIM * 2;  // ~16.03 MB
    const size_t rowbytes = (size_t)N_CELLS * sizeof(float);     // 32 KB
    const size_t avail = (ws_size > fixed) ? (ws_size - fixed) : 0;
    int R = (int)((avail / rowbytes) / TILE) * TILE;
    if (R > 2048) R = 2048;

    norms_kernel<<<N_CELLS / 4, 256, 0, stream>>>(E, norms, out);

    if (R >= TILE) {
        convert_kernel<<<(N_CELLS * DIM) / (256 * 4), 256, 0, stream>>>(E, Eh, El);
        for (int r0 = 0; r0 < N_CELLS; r0 += R) {
            const int rows = (N_CELLS - r0 < R) ? (N_CELLS - r0) : R;
            dim3 g(N_CELLS / TILE, rows / TILE);
            dist_mfma_kernel<<<g, 256, 0, stream>>>(Eh, El, norms, Dm, r0);
            loss_kernel<<<rows, 256, 0, stream>>>(Dm, labels, out);
        }
    } else {
        fused_kernel<<<N_CELLS, 256, 0, stream>>>(E, norms, labels, out);
    }
}